// Round 8
// baseline (375.359 us; speedup 1.0000x reference)
//
#include <hip/hip_runtime.h>

#define BB 8
#define NN 2048
#define FF 64
#define HH 32
#define CK 128          // K per chunk
#define NCHK (NN / CK)  // 16 chunks
#define ROWB 272        // padded LDS row stride (bytes) = 17 granules of 16B

typedef __attribute__((ext_vector_type(8))) short short8;
typedef __attribute__((ext_vector_type(4))) float floatx4;

static __device__ __forceinline__ float warp_sum64(float v) {
  for (int off = 32; off; off >>= 1) v += __shfl_down(v, off, 64);
  return v;
}

static __device__ __forceinline__ unsigned int f2bf_rne(float f) {
  unsigned int u = __float_as_uint(f);
  return (u + 0x7fffu + ((u >> 16) & 1u)) >> 16;
}
static __device__ __forceinline__ float bf2f(unsigned short s) {
  return __uint_as_float(((unsigned int)s) << 16);
}

// d_i = rowsum(a) + add_i ; dm = d^-1/2 ; add_i = (|a_ii| < 1e-7)
// Also converts A to bf16 (RNE) into Abf, fused with the mandatory read.
__global__ __launch_bounds__(256) void deg_cvt_kernel(const float* __restrict__ A,
                                                      float* __restrict__ dm,
                                                      float* __restrict__ addf,
                                                      unsigned short* __restrict__ Abf) {
  const int lane = threadIdx.x & 63;
  const int w = threadIdx.x >> 6;
  const size_t row = (size_t)blockIdx.x * 4 + w;  // flat b*N + n
  const size_t n = row & (NN - 1);
  const float* Ar = A + row * (size_t)NN;
  unsigned int* Abr = (unsigned int*)(Abf + row * (size_t)NN);
  float sum = 0.f;
#pragma unroll
  for (int it = 0; it < 8; ++it) {
    float4 v = *(const float4*)(Ar + it * 256 + lane * 4);
    sum += v.x + v.y + v.z + v.w;
    uint2 p;
    p.x = f2bf_rne(v.x) | (f2bf_rne(v.y) << 16);
    p.y = f2bf_rne(v.z) | (f2bf_rne(v.w) << 16);
    *(uint2*)(Abr + it * 128 + lane * 2) = p;
  }
  sum = warp_sum64(sum);
  if (lane == 0) {
    const float diag = Ar[n];
    const float ad = (fabsf(diag) < 1e-7f) ? 1.f : 0.f;
    dm[row] = 1.f / sqrtf(sum + ad);
    addf[row] = ad;
  }
}

// hst1[b][f][n] = bf16( dm_row * sum_c x[row][c] * W1[c][f] ), row = b*N+n
__global__ __launch_bounds__(256) void xw_kernel(const float* __restrict__ x,
                                                 const float* __restrict__ W1,
                                                 const float* __restrict__ dm,
                                                 unsigned short* __restrict__ hst) {
  __shared__ float xs[8][FF + 1];
  __shared__ float wl[FF * HH];
  const int tid = threadIdx.x;
  const size_t row0 = (size_t)blockIdx.x * 8;
  for (int k = tid; k < FF * HH; k += 256) wl[k] = W1[k];
  for (int k = tid; k < 8 * FF; k += 256) xs[k >> 6][k & 63] = x[row0 * FF + k];
  __syncthreads();
  const int r = tid >> 5, c = tid & 31;
  float acc = 0.f;
#pragma unroll
  for (int k = 0; k < FF; ++k) acc = fmaf(xs[r][k], wl[k * HH + c], acc);
  const size_t row = row0 + r;
  const int b = (int)(row >> 11);
  const int n = (int)(row & (NN - 1));
  hst[((size_t)b * HH + c) * NN + n] = (unsigned short)f2bf_rne(dm[row] * acc);
}

// One fused GCN layer via MFMA. Staging transport: per-lane global b128
// loads -> VGPR -> ds_write_b128 -> LDS (NOT global_load_lds: its barrier
// drain can't be pipelined at HIP level; per-lane loads get precise
// per-register vmcnt so chunk c+2's loads stay in flight across barriers).
// Block: 4 waves, M-tile 32, N=32, K=2048 in 16 chunks of 128. Wave w owns
// (mt=w>>1, nt=w&1). LDS rows padded to 272 B -> 2-way bank conflicts (free).
// One barrier per chunk (double-buffered; write of buf p at iter c+2 is
// ordered against reads of buf p at iter c by iter c+1's barrier).
__global__ __launch_bounds__(256) void layer_kernel(const unsigned short* __restrict__ Abf,
                                                    const unsigned short* __restrict__ hst_in,
                                                    const float* __restrict__ dm,
                                                    const float* __restrict__ addf,
                                                    const float* __restrict__ bias,
                                                    const float* __restrict__ Wn,
                                                    unsigned short* __restrict__ hst_next,
                                                    unsigned int* __restrict__ gmax,
                                                    const int do_pool) {
  __shared__ __align__(16) unsigned char sbuf[2][64 * ROWB];  // A rows 0-31, B rows 32-63
  __shared__ float wl[HH * HH];
  __shared__ float hbuf[32][HH + 1];
  __shared__ float pbuf[8][HH];

  const int tid = threadIdx.x;
  const int mb = blockIdx.x & 63;
  const int b = blockIdx.x >> 6;
  const int mrow0 = mb * 32;
  const int lane = tid & 63;
  const int w = tid >> 6;
  const int mt = w >> 1, nt = w & 1;

  if (!do_pool)
    for (int k = tid; k < HH * HH; k += 256) wl[k] = Wn[k];

  // --- staging map: thread t covers row ra=t>>3 (A and B), granules t&7 and 8+(t&7) ---
  const int ra = tid >> 3;
  const int g0 = tid & 7;
  const unsigned short* __restrict__ aS =
      Abf + ((size_t)(b * NN + mrow0 + ra)) * NN + g0 * 8;
  const unsigned short* __restrict__ bS =
      hst_in + ((size_t)(b * HH + ra)) * NN + g0 * 8;
  const int adst0 = ra * ROWB + g0 * 16;
  const int adst1 = ra * ROWB + (8 + g0) * 16;
  const int bdst0 = (32 + ra) * ROWB + g0 * 16;
  const int bdst1 = (32 + ra) * ROWB + (8 + g0) * 16;

  // --- fragment read offsets ---
  const int q = lane >> 4;
  const int l15 = lane & 15;
  const int arow = mt * 16 + l15;
  const int brow = 32 + nt * 16 + l15;

  floatx4 acc = {0.f, 0.f, 0.f, 0.f};

  // register double-buffer of staged chunks (each: 4 x uint4 per thread)
  uint4 rA0[2], rA1[2], rB0[2], rB1[2];
#define GLOAD(p, kc)                                  \
  do {                                                \
    rA0[p] = *(const uint4*)(aS + (kc));              \
    rA1[p] = *(const uint4*)(aS + (kc) + 64);         \
    rB0[p] = *(const uint4*)(bS + (kc));              \
    rB1[p] = *(const uint4*)(bS + (kc) + 64);         \
  } while (0)

  GLOAD(0, 0);
  GLOAD(1, CK);
#pragma unroll
  for (int c = 0; c < NCHK; ++c) {
    const int p = c & 1;
    // stage chunk c (vmcnt waits only on these 4 registers)
    *(uint4*)(&sbuf[p][adst0]) = rA0[p];
    *(uint4*)(&sbuf[p][adst1]) = rA1[p];
    *(uint4*)(&sbuf[p][bdst0]) = rB0[p];
    *(uint4*)(&sbuf[p][bdst1]) = rB1[p];
    __syncthreads();
    if (c + 2 < NCHK) GLOAD(p, (c + 2) * CK);  // stays in flight 2 chunks
    const unsigned char* base = sbuf[p];
#pragma unroll
    for (int s = 0; s < 4; ++s) {
      short8 af = *(const short8*)(base + arow * ROWB + s * 64 + q * 16);
      short8 bf = *(const short8*)(base + brow * ROWB + s * 64 + q * 16);
      acc = __builtin_amdgcn_mfma_f32_16x16x32_bf16(af, bf, acc, 0, 0, 0);
    }
  }
#undef GLOAD

  // --- epilogue: h = relu(dm*(acc + add*hs_in) + bias) ---
  const int colc = nt * 16 + l15;
  __syncthreads();
#pragma unroll
  for (int r = 0; r < 4; ++r) {
    const int rowb = mt * 16 + q * 4 + r;
    const int rg = b * NN + mrow0 + rowb;
    const float hsin = bf2f(hst_in[((size_t)b * HH + colc) * NN + mrow0 + rowb]);
    const float h = fmaf(dm[rg], acc[r] + addf[rg] * hsin, bias[colc]);
    hbuf[rowb][colc] = fmaxf(h, 0.f);
  }
  __syncthreads();

  const int col = tid & 31;
  const int rq = tid >> 5;  // 0..7 -> rows rq*4 .. rq*4+3
  if (do_pool) {
    float m = hbuf[rq * 4][col];
#pragma unroll
    for (int i = 1; i < 4; ++i) m = fmaxf(m, hbuf[rq * 4 + i][col]);
    pbuf[rq][col] = m;
    __syncthreads();
    if (tid < HH) {
      float mm = pbuf[0][tid];
#pragma unroll
      for (int r = 1; r < 8; ++r) mm = fmaxf(mm, pbuf[r][tid]);
      atomicMax(&gmax[b * HH + tid], __float_as_uint(mm));
    }
  } else {
    unsigned short outv[4];
#pragma unroll
    for (int i = 0; i < 4; ++i) {
      const int row = rq * 4 + i;
      const int rg = b * NN + mrow0 + row;
      float acc2 = 0.f;
#pragma unroll
      for (int k = 0; k < HH; ++k)
        acc2 = fmaf(hbuf[row][k], wl[k * HH + col], acc2);
      outv[i] = (unsigned short)f2bf_rne(dm[rg] * acc2);
    }
    *(ushort4*)(hst_next + ((size_t)b * HH + col) * NN + mrow0 + rq * 4) =
        *(ushort4*)outv;
  }
}

// out[b] = (relu(g @ Wf1 + bf1)) @ Wf2 + bf2 ; one wave per batch
__global__ __launch_bounds__(64) void head_kernel(const unsigned int* __restrict__ gmax,
                                                  const float* __restrict__ Wf1,
                                                  const float* __restrict__ bf1,
                                                  const float* __restrict__ Wf2,
                                                  const float* __restrict__ bf2,
                                                  float* __restrict__ out) {
  const int b = blockIdx.x;
  const int t = threadIdx.x;  // 0..63 hidden units
  float acc = bf1[t];
#pragma unroll
  for (int c = 0; c < HH; ++c)
    acc = fmaf(__uint_as_float(gmax[b * HH + c]), Wf1[c * (2 * HH) + t], acc);
  acc = fmaxf(acc, 0.f);
  float v = acc * Wf2[t];
  v = warp_sum64(v);
  if (t == 0) out[b] = v + bf2[0];
}

extern "C" void kernel_launch(void* const* d_in, const int* in_sizes, int n_in,
                              void* d_out, int out_size, void* d_ws, size_t ws_size,
                              hipStream_t stream) {
  const float* x   = (const float*)d_in[0];
  const float* a   = (const float*)d_in[1];
  const float* W1  = (const float*)d_in[2];
  const float* b1  = (const float*)d_in[3];
  const float* W2  = (const float*)d_in[4];
  const float* b2  = (const float*)d_in[5];
  const float* W3  = (const float*)d_in[6];
  const float* b3  = (const float*)d_in[7];
  const float* Wf1 = (const float*)d_in[8];
  const float* bf1 = (const float*)d_in[9];
  const float* Wf2 = (const float*)d_in[10];
  const float* bf2 = (const float*)d_in[11];
  float* out = (float*)d_out;

  float* ws = (float*)d_ws;
  const size_t BN = (size_t)BB * NN;  // 16384
  float* dm   = ws;                                       // 16384 f
  float* addf = dm + BN;                                  // 16384 f
  unsigned int* gmax = (unsigned int*)(addf + BN);        // 256 u32
  unsigned short* hst_a = (unsigned short*)(gmax + 256);  // 1 MB
  unsigned short* hst_b = hst_a + BN * HH;                // 1 MB
  unsigned short* Abf = hst_b + BN * HH;                  // 67 MB bf16 A
  // total ws use ~69.5 MB

  hipMemsetAsync(gmax, 0, BB * HH * sizeof(unsigned int), stream);

  deg_cvt_kernel<<<BN / 4, 256, 0, stream>>>(a, dm, addf, Abf);
  xw_kernel<<<BN / 8, 256, 0, stream>>>(x, W1, dm, hst_a);

  layer_kernel<<<BB * 64, 256, 0, stream>>>(Abf, hst_a, dm, addf, b1, W2, hst_b, nullptr, 0);
  layer_kernel<<<BB * 64, 256, 0, stream>>>(Abf, hst_b, dm, addf, b2, W3, hst_a, nullptr, 0);
  layer_kernel<<<BB * 64, 256, 0, stream>>>(Abf, hst_a, dm, addf, b3, nullptr, nullptr, gmax, 1);

  head_kernel<<<BB, 64, 0, stream>>>(gmax, Wf1, bf1, Wf2, bf2, out);
}